// Round 1
// baseline (88.820 us; speedup 1.0000x reference)
//
#include <hip/hip_runtime.h>

// SpectralConv2D_T: B=64,H=32,W=32,C=8, F=64,K=3, VALID/stride1 -> O=30x30, L=900, N=1024
// out[b,r,c,f] = relu( sum_{i,j} base[f,i,j] * (enc[n]-dec[l]) * up[b,n] ),
//   n=(r+i)*32+(c+j), l=r*30+c, up = channel-mean of inputs,
//   base[f,i,j] = omega[f,i,j]*(lam_in[i]-lam_out[j]) with omega assembled from
//   diag (F,3), triu order (0,1),(0,2),(1,2), tril order (1,0),(2,0),(2,1).

#define SPL 4  // position-splits per image; grid = 64*SPL blocks

__global__ __launch_bounds__(256) void spectral_conv_kernel(
    const float* __restrict__ inputs,   // (64,32,32,8)
    const float* __restrict__ om_diag,  // (64,3)
    const float* __restrict__ om_triu,  // (1,192)
    const float* __restrict__ om_tril,  // (1,192)
    const float* __restrict__ lam_in,   // (3,1)
    const float* __restrict__ lam_out,  // (1,3)
    const float* __restrict__ enc,      // (1,1024)
    const float* __restrict__ dec,      // (900,1)
    float* __restrict__ out)            // (64,30,30,64)
{
    __shared__ float up_s[1024];
    __shared__ float enc_s[1024];

    const int tid   = threadIdx.x;
    const int b     = (int)blockIdx.x & 63;
    const int split = (int)blockIdx.x >> 6;

    // ---- Phase 1: channel mean (over C=8) into LDS; also stage encode vec ----
    const float* img = inputs + (size_t)b * 8192;  // 1024 * 8
    #pragma unroll
    for (int k = 0; k < 4; ++k) {
        int m = tid + 256 * k;                     // n index
        const float4* p4 = (const float4*)(img + m * 8);
        float4 a = p4[0];
        float4 q = p4[1];
        up_s[m]  = (a.x + a.y + a.z + a.w + q.x + q.y + q.z + q.w) * 0.125f;
        enc_s[m] = enc[m];
    }
    __syncthreads();

    // ---- Per-thread filter weights (lane = filter) ----
    const int f   = tid & 63;
    const int wid = tid >> 6;  // wave id 0..3
    const float li0 = lam_in[0],  li1 = lam_in[1],  li2 = lam_in[2];
    const float lo0 = lam_out[0], lo1 = lam_out[1], lo2 = lam_out[2];
    const float w00 = om_diag[f * 3 + 0] * (li0 - lo0);
    const float w01 = om_triu[f * 3 + 0] * (li0 - lo1);
    const float w02 = om_triu[f * 3 + 1] * (li0 - lo2);
    const float w10 = om_tril[f * 3 + 0] * (li1 - lo0);
    const float w11 = om_diag[f * 3 + 1] * (li1 - lo1);
    const float w12 = om_triu[f * 3 + 2] * (li1 - lo2);
    const float w20 = om_tril[f * 3 + 1] * (li2 - lo0);
    const float w21 = om_tril[f * 3 + 2] * (li2 - lo1);
    const float w22 = om_diag[f * 3 + 2] * (li2 - lo2);

    float* outb = out + (size_t)b * (900 * 64);

    // ---- Phase 2: each wave sweeps positions; lanes = filters (coalesced store) ----
    for (int p = split * 4 + wid; p < 900; p += 4 * SPL) {
        const int r  = p / 30;
        const int c  = p - r * 30;
        const int n0 = r * 32 + c;
        const float dl = dec[p];

        float v, acc;
        v = up_s[n0 +  0] * (enc_s[n0 +  0] - dl); acc = w00 * v;
        v = up_s[n0 +  1] * (enc_s[n0 +  1] - dl); acc = fmaf(w01, v, acc);
        v = up_s[n0 +  2] * (enc_s[n0 +  2] - dl); acc = fmaf(w02, v, acc);
        v = up_s[n0 + 32] * (enc_s[n0 + 32] - dl); acc = fmaf(w10, v, acc);
        v = up_s[n0 + 33] * (enc_s[n0 + 33] - dl); acc = fmaf(w11, v, acc);
        v = up_s[n0 + 34] * (enc_s[n0 + 34] - dl); acc = fmaf(w12, v, acc);
        v = up_s[n0 + 64] * (enc_s[n0 + 64] - dl); acc = fmaf(w20, v, acc);
        v = up_s[n0 + 65] * (enc_s[n0 + 65] - dl); acc = fmaf(w21, v, acc);
        v = up_s[n0 + 66] * (enc_s[n0 + 66] - dl); acc = fmaf(w22, v, acc);

        outb[p * 64 + f] = fmaxf(acc, 0.0f);
    }
}

extern "C" void kernel_launch(void* const* d_in, const int* in_sizes, int n_in,
                              void* d_out, int out_size, void* d_ws, size_t ws_size,
                              hipStream_t stream) {
    const float* inputs  = (const float*)d_in[0];
    const float* om_diag = (const float*)d_in[1];
    const float* om_triu = (const float*)d_in[2];
    const float* om_tril = (const float*)d_in[3];
    const float* lam_in  = (const float*)d_in[4];
    const float* lam_out = (const float*)d_in[5];
    const float* enc     = (const float*)d_in[6];
    const float* dec     = (const float*)d_in[7];
    float* out = (float*)d_out;

    dim3 grid(64 * SPL);
    dim3 block(256);
    spectral_conv_kernel<<<grid, block, 0, stream>>>(
        inputs, om_diag, om_triu, om_tril, lam_in, lam_out, enc, dec, out);
}

// Round 2
// 79.118 us; speedup vs baseline: 1.1226x; 1.1226x over previous
//
#include <hip/hip_runtime.h>

// SpectralConv2D_T: B=64,H=32,W=32,C=8, F=64,K=3, VALID/stride1 -> O=30x30, L=900, N=1024
// out[b,r,c,f] = relu( sum_{i,j} w[f,i,j] * (enc[n]-dec[l]) * up[b,n] )
//             = relu( sum w*ue[n]  -  dec[l] * sum w*up[n] ),  ue[n]=up[n]*enc[n]
//   n=(r+i)*32+(c+j), l=r*30+c, up = channel-mean of inputs,
//   w[f,i,j] = omega[f,i,j]*(lam_in[i]-lam_out[j]); omega from diag (F,3),
//   triu order (0,1),(0,2),(1,2), tril order (1,0),(2,0),(2,1).

#define SPL 16  // position-splits per image; grid = 64*SPL = 1024 blocks (4/CU)

__global__ __launch_bounds__(256) void spectral_conv_kernel(
    const float* __restrict__ inputs,   // (64,32,32,8)
    const float* __restrict__ om_diag,  // (64,3)
    const float* __restrict__ om_triu,  // (1,192)
    const float* __restrict__ om_tril,  // (1,192)
    const float* __restrict__ lam_in,   // (3,1)
    const float* __restrict__ lam_out,  // (1,3)
    const float* __restrict__ enc,      // (1,1024)
    const float* __restrict__ dec,      // (900,1)
    float* __restrict__ out)            // (64,30,30,64)
{
    __shared__ float up_s[1024];
    __shared__ float ue_s[1024];

    const int tid   = threadIdx.x;
    const int b     = (int)blockIdx.x & 63;
    const int split = (int)blockIdx.x >> 6;

    // ---- Phase 1: channel mean (C=8) into LDS; ue = up * enc ----
    const float* img = inputs + (size_t)b * 8192;  // 1024 * 8
    #pragma unroll
    for (int k = 0; k < 4; ++k) {
        int m = tid + 256 * k;                     // n index
        const float4* p4 = (const float4*)(img + m * 8);
        float4 a = p4[0];
        float4 q = p4[1];
        float u = (a.x + a.y + a.z + a.w + q.x + q.y + q.z + q.w) * 0.125f;
        up_s[m] = u;
        ue_s[m] = u * enc[m];
    }
    __syncthreads();

    // ---- Per-thread filter weights (lane = filter) ----
    const int f   = tid & 63;
    const int wid = tid >> 6;  // wave id 0..3
    const float li0 = lam_in[0],  li1 = lam_in[1],  li2 = lam_in[2];
    const float lo0 = lam_out[0], lo1 = lam_out[1], lo2 = lam_out[2];
    const float w00 = om_diag[f * 3 + 0] * (li0 - lo0);
    const float w01 = om_triu[f * 3 + 0] * (li0 - lo1);
    const float w02 = om_triu[f * 3 + 1] * (li0 - lo2);
    const float w10 = om_tril[f * 3 + 0] * (li1 - lo0);
    const float w11 = om_diag[f * 3 + 1] * (li1 - lo1);
    const float w12 = om_triu[f * 3 + 2] * (li1 - lo2);
    const float w20 = om_tril[f * 3 + 1] * (li2 - lo0);
    const float w21 = om_tril[f * 3 + 2] * (li2 - lo1);
    const float w22 = om_diag[f * 3 + 2] * (li2 - lo2);

    float* outb = out + (size_t)b * (900 * 64);

    // ---- Phase 2: waves sweep positions; lanes = filters (coalesced 256B store) ----
    for (int p = split * 4 + wid; p < 900; p += 4 * SPL) {
        const int r  = p / 30;
        const int c  = p - r * 30;
        const int n0 = r * 32 + c;
        const float dl = dec[p];

        float s1, s2;
        s1 = w00 * ue_s[n0 +  0];            s2 = w00 * up_s[n0 +  0];
        s1 = fmaf(w01, ue_s[n0 +  1], s1);   s2 = fmaf(w01, up_s[n0 +  1], s2);
        s1 = fmaf(w02, ue_s[n0 +  2], s1);   s2 = fmaf(w02, up_s[n0 +  2], s2);
        s1 = fmaf(w10, ue_s[n0 + 32], s1);   s2 = fmaf(w10, up_s[n0 + 32], s2);
        s1 = fmaf(w11, ue_s[n0 + 33], s1);   s2 = fmaf(w11, up_s[n0 + 33], s2);
        s1 = fmaf(w12, ue_s[n0 + 34], s1);   s2 = fmaf(w12, up_s[n0 + 34], s2);
        s1 = fmaf(w20, ue_s[n0 + 64], s1);   s2 = fmaf(w20, up_s[n0 + 64], s2);
        s1 = fmaf(w21, ue_s[n0 + 65], s1);   s2 = fmaf(w21, up_s[n0 + 65], s2);
        s1 = fmaf(w22, ue_s[n0 + 66], s1);   s2 = fmaf(w22, up_s[n0 + 66], s2);

        outb[p * 64 + f] = fmaxf(fmaf(-dl, s2, s1), 0.0f);
    }
}

extern "C" void kernel_launch(void* const* d_in, const int* in_sizes, int n_in,
                              void* d_out, int out_size, void* d_ws, size_t ws_size,
                              hipStream_t stream) {
    const float* inputs  = (const float*)d_in[0];
    const float* om_diag = (const float*)d_in[1];
    const float* om_triu = (const float*)d_in[2];
    const float* om_tril = (const float*)d_in[3];
    const float* lam_in  = (const float*)d_in[4];
    const float* lam_out = (const float*)d_in[5];
    const float* enc     = (const float*)d_in[6];
    const float* dec     = (const float*)d_in[7];
    float* out = (float*)d_out;

    dim3 grid(64 * SPL);
    dim3 block(256);
    spectral_conv_kernel<<<grid, block, 0, stream>>>(
        inputs, om_diag, om_triu, om_tril, lam_in, lam_out, enc, dec, out);
}

// Round 3
// 78.293 us; speedup vs baseline: 1.1345x; 1.0105x over previous
//
#include <hip/hip_runtime.h>

// SpectralConv2D_T: B=64,H=32,W=32,C=8, F=64,K=3, VALID/stride1 -> O=30x30, L=900, N=1024
// out[b,r,c,f] = relu( sum_{i,j} w[f,i,j]*(enc[n]-dec[l])*up[b,n] )
//             = relu( S1 - dec[l]*S2 ),  S1=conv(ue), S2=conv(up), ue=up*enc
// w[f,i,j] = omega[f,i,j]*(lam_in[i]-lam_out[j]); omega from diag (F,3),
// triu order (0,1),(0,2),(1,2), tril order (1,0),(2,0),(2,1).
//
// Layout: grid = 64 images x 30 splits; block = 256 (4 waves). Each wave owns one
// "super-group" = 2 output rows x 4 cols. Input taps for the 8 positions = 4 row
// windows x 8 floats, loaded as 16 ds_read_b128 broadcasts (vs 144 b32) to unload
// the LDS pipe. Lane = filter -> 256B coalesced stores.

#define SPL 30  // splits per image; 30 splits x 4 waves = 120 super-groups = 15 row-pairs x 8 col-groups

__global__ __launch_bounds__(256) void spectral_conv_kernel(
    const float* __restrict__ inputs,   // (64,32,32,8)
    const float* __restrict__ om_diag,  // (64,3)
    const float* __restrict__ om_triu,  // (1,192)
    const float* __restrict__ om_tril,  // (1,192)
    const float* __restrict__ lam_in,   // (3,1)
    const float* __restrict__ lam_out,  // (1,3)
    const float* __restrict__ enc,      // (1,1024)
    const float* __restrict__ dec,      // (900,1)
    float* __restrict__ out)            // (64,30,30,64)
{
    __shared__ float4 up4[257];  // 1024 floats + 4 pad (row31/cb28 window tail)
    __shared__ float4 ue4[257];
    float* up_s = (float*)up4;
    float* ue_s = (float*)ue4;

    const int tid   = threadIdx.x;
    const int b     = (int)blockIdx.x & 63;
    const int split = (int)blockIdx.x >> 6;   // 0..29

    // ---- Phase 1: channel mean (C=8) into LDS; ue = up * enc ----
    const float* img = inputs + (size_t)b * 8192;
    #pragma unroll
    for (int k = 0; k < 4; ++k) {
        int m = tid + 256 * k;
        const float4* p4 = (const float4*)(img + m * 8);
        float4 a = p4[0];
        float4 q = p4[1];
        float u = (a.x + a.y + a.z + a.w + q.x + q.y + q.z + q.w) * 0.125f;
        up_s[m] = u;
        ue_s[m] = u * enc[m];
    }
    __syncthreads();

    // ---- Per-lane filter weights ----
    const int f   = tid & 63;
    const int wid = tid >> 6;
    const float li0 = lam_in[0],  li1 = lam_in[1],  li2 = lam_in[2];
    const float lo0 = lam_out[0], lo1 = lam_out[1], lo2 = lam_out[2];
    const float w00 = om_diag[f * 3 + 0] * (li0 - lo0);
    const float w01 = om_triu[f * 3 + 0] * (li0 - lo1);
    const float w02 = om_triu[f * 3 + 1] * (li0 - lo2);
    const float w10 = om_tril[f * 3 + 0] * (li1 - lo0);
    const float w11 = om_diag[f * 3 + 1] * (li1 - lo1);
    const float w12 = om_triu[f * 3 + 2] * (li1 - lo2);
    const float w20 = om_tril[f * 3 + 1] * (li2 - lo0);
    const float w21 = om_tril[f * 3 + 2] * (li2 - lo1);
    const float w22 = om_diag[f * 3 + 2] * (li2 - lo2);

    // ---- Phase 2: one super-group per wave (2 rows x 4 cols) ----
    const int sg = split * 4 + wid;      // 0..119
    const int r0 = (sg >> 3) * 2;        // 0,2,...,28
    const int cb = (sg & 7) * 4;         // 0,4,...,28

    float Ur[4][8], Er[4][8];            // 4 row windows x 8 floats
    #pragma unroll
    for (int rw = 0; rw < 4; ++rw) {
        int b4 = (((r0 + rw) << 5) + cb) >> 2;   // 16B-aligned (cb%4==0)
        *(float4*)&Ur[rw][0] = up4[b4];
        *(float4*)&Ur[rw][4] = up4[b4 + 1];
        *(float4*)&Er[rw][0] = ue4[b4];
        *(float4*)&Er[rw][4] = ue4[b4 + 1];
    }

    const int p0 = r0 * 30 + cb;
    float* outb = out + (size_t)b * (900 * 64);

    #pragma unroll
    for (int q = 0; q < 4; ++q) {
        if (cb + q < 30) {
            // output row r0 (tap rows 0,1,2)
            float s1 = w00 * Er[0][q];
            float s2 = w00 * Ur[0][q];
            s1 = fmaf(w01, Er[0][q+1], s1);  s2 = fmaf(w01, Ur[0][q+1], s2);
            s1 = fmaf(w02, Er[0][q+2], s1);  s2 = fmaf(w02, Ur[0][q+2], s2);
            s1 = fmaf(w10, Er[1][q  ], s1);  s2 = fmaf(w10, Ur[1][q  ], s2);
            s1 = fmaf(w11, Er[1][q+1], s1);  s2 = fmaf(w11, Ur[1][q+1], s2);
            s1 = fmaf(w12, Er[1][q+2], s1);  s2 = fmaf(w12, Ur[1][q+2], s2);
            s1 = fmaf(w20, Er[2][q  ], s1);  s2 = fmaf(w20, Ur[2][q  ], s2);
            s1 = fmaf(w21, Er[2][q+1], s1);  s2 = fmaf(w21, Ur[2][q+1], s2);
            s1 = fmaf(w22, Er[2][q+2], s1);  s2 = fmaf(w22, Ur[2][q+2], s2);
            float dl0 = dec[p0 + q];
            outb[(p0 + q) * 64 + f] = fmaxf(fmaf(-dl0, s2, s1), 0.0f);

            // output row r0+1 (tap rows 1,2,3)
            float t1 = w00 * Er[1][q];
            float t2 = w00 * Ur[1][q];
            t1 = fmaf(w01, Er[1][q+1], t1);  t2 = fmaf(w01, Ur[1][q+1], t2);
            t1 = fmaf(w02, Er[1][q+2], t1);  t2 = fmaf(w02, Ur[1][q+2], t2);
            t1 = fmaf(w10, Er[2][q  ], t1);  t2 = fmaf(w10, Ur[2][q  ], t2);
            t1 = fmaf(w11, Er[2][q+1], t1);  t2 = fmaf(w11, Ur[2][q+1], t2);
            t1 = fmaf(w12, Er[2][q+2], t1);  t2 = fmaf(w12, Ur[2][q+2], t2);
            t1 = fmaf(w20, Er[3][q  ], t1);  t2 = fmaf(w20, Ur[3][q  ], t2);
            t1 = fmaf(w21, Er[3][q+1], t1);  t2 = fmaf(w21, Ur[3][q+1], t2);
            t1 = fmaf(w22, Er[3][q+2], t1);  t2 = fmaf(w22, Ur[3][q+2], t2);
            float dl1 = dec[p0 + 30 + q];
            outb[(p0 + 30 + q) * 64 + f] = fmaxf(fmaf(-dl1, t2, t1), 0.0f);
        }
    }
}

extern "C" void kernel_launch(void* const* d_in, const int* in_sizes, int n_in,
                              void* d_out, int out_size, void* d_ws, size_t ws_size,
                              hipStream_t stream) {
    const float* inputs  = (const float*)d_in[0];
    const float* om_diag = (const float*)d_in[1];
    const float* om_triu = (const float*)d_in[2];
    const float* om_tril = (const float*)d_in[3];
    const float* lam_in  = (const float*)d_in[4];
    const float* lam_out = (const float*)d_in[5];
    const float* enc     = (const float*)d_in[6];
    const float* dec     = (const float*)d_in[7];
    float* out = (float*)d_out;

    dim3 grid(64 * SPL);
    dim3 block(256);
    spectral_conv_kernel<<<grid, block, 0, stream>>>(
        inputs, om_diag, om_triu, om_tril, lam_in, lam_out, enc, dec, out);
}